// Round 11
// baseline (1294.639 us; speedup 1.0000x reference)
//
#include <hip/hip_runtime.h>
#include <math.h>
#include <stdint.h>

// Problem constants
#define DD 500
#define BB 512
// Permuted N layout: slab s (0..63) owns cols [32s, 32s+32) = [r|z|i_n|h_n]
// for d in [8s, 8s+8).  r/z cols hold x@(Wih+Whh) for t>=1 (x==h); t=0 uses
// Wp0 (Wih only in r/z).
// Split-precision: C = Ah·Wh + Al·Wh + Ah·Wl.  Wp k-order: [Wh|Wh|Wl]
// (96 ksteps).  Ap holds only [Ah|Al] (64 ksteps, K=1024); the GEMM's third
// phase re-reads the Ah region from LDS.
#define NSTRIPS 64     // n-strips (slabs) of 32
#define MSTRIPS 16     // m-strips of 32
#define WKSTEPS 96     // Wp ksteps of 16
#define AKSTEPS 64     // Ap ksteps of 16 ([Ah|Al])
#define NELEM (BB*DD)
// Persistent grid: 16 row-groups x 8 col-groups = 128 blocks.
// bid%8 = col-group (= XCD round-robin -> each XCD L2 serves ONE Wp slice).
#define GM 16
#define GN 8
#define NBLK 128
#define HSTRIDE 2048   // floats per (block, hist slot): 32 rows x 64 d

typedef _Float16 f16;
typedef _Float16 f16x8 __attribute__((ext_vector_type(8)));
typedef float    f32x16 __attribute__((ext_vector_type(16)));
typedef unsigned u32x4  __attribute__((ext_vector_type(4)));

#define APCNT ((size_t)MSTRIPS * AKSTEPS * 64 * 8)  // f16 per Ap buffer (1MB)
#define WPCNT ((size_t)NSTRIPS * WKSTEPS * 64 * 8)  // f16 per Wp buffer

// Fragment-order layout (Ap and Wp):
//   elem(strip, kstep, ln, j) at ((strip*KS + kstep)*64 + ln)*8 + j
//   row = strip*32 + (ln&31),  k = kstep*16 + (ln>>5)*8 + j
// = the mfma_f32_32x32x16_f16 A/B operand layout.

__device__ __forceinline__ float aload_f32(const float* p) {
    return __hip_atomic_load(p, __ATOMIC_RELAXED, __HIP_MEMORY_SCOPE_AGENT);
}
// Coalesced device-scope 16B load/store (sc0 sc1: bypass L1/L2, served at the
// device coherence point). asm volatile: ordered, registers forced live.
__device__ __forceinline__ void aload16i(u32x4& d, const f16* p) {
    asm volatile("global_load_dwordx4 %0, %1, off sc0 sc1"
                 : "=&v"(d) : "v"(p) : "memory");
}
__device__ __forceinline__ void astore16(f16* p, u32x4 v) {
    asm volatile("global_store_dwordx4 %0, %1, off sc0 sc1"
                 :: "v"(p), "v"(v) : "memory");
}

// fast sigmoid/tanh via hardware v_exp: rel err ~1e-6
__device__ __forceinline__ float fsigmoid(float x) {
    return 1.0f / (1.0f + __expf(-x));
}
__device__ __forceinline__ float ftanh(float x) {
    return 2.0f / (1.0f + __expf(-2.0f * x)) - 1.0f;
}

// ---------------------------------------------------------------------------
// Wp0 (t=0) and Wp1 (t>=1), frag order, PERMUTED cols. k-blocks: [Wh|Wh|Wl].
// ---------------------------------------------------------------------------
__global__ __launch_bounds__(256) void conv_w(const float* __restrict__ Wih,
                                              const float* __restrict__ Whh,
                                              f16* __restrict__ Wp0,
                                              f16* __restrict__ Wp1)
{
    int p = blockIdx.x * 256 + threadIdx.x;    // (strip, kstep, ln)
    const int ln = p & 63; p >>= 6;
    const int kstep = p % WKSTEPS;
    const int strip = p / WKSTEPS;             // slab s, 0..63
    const int q = ln & 31;                     // col within slab
    const int g = q >> 3;                      // 0 r, 1 z, 2 i_n, 3 h_n
    const int d = strip * 8 + (q & 7);         // 0..511
    const int kb0 = kstep * 16 + (ln >> 5) * 8;
    const int blk = kb0 >> 9, bk0 = kb0 & 511;
    const float* pih = 0;
    const float* phh = 0;
    if (d < DD) {
        if (g == 0)      { pih = Wih + (size_t)d * DD;
                           phh = Whh + (size_t)d * DD; }
        else if (g == 1) { pih = Wih + (size_t)(500 + d) * DD;
                           phh = Whh + (size_t)(500 + d) * DD; }
        else if (g == 2) { pih = Wih + (size_t)(1000 + d) * DD; }
        else             { phh = Whh + (size_t)(1000 + d) * DD; }
    }
    f16 o0[8], o1[8];
    #pragma unroll
    for (int j = 0; j < 8; ++j) {
        const int bk = bk0 + j;
        float vi = 0.f, vh = 0.f;
        if (bk < DD) {
            if (pih) vi = pih[bk];
            if (phh) vh = phh[bk];
        }
        const float v0 = (g == 3) ? vh : vi;           // Wp0 value
        const float v1 = (g <= 1) ? (vi + vh) : v0;    // Wp1 value
        f16 h0 = (f16)v0;
        f16 h1 = (f16)v1;
        o0[j] = (blk == 2) ? (f16)(v0 - (float)h0) : h0;
        o1[j] = (blk == 2) ? (f16)(v1 - (float)h1) : h1;
    }
    const size_t off = ((size_t)(strip * WKSTEPS + kstep) * 64 + ln) * 8;
    *(uint4*)(Wp0 + off) = *(uint4*)o0;
    *(uint4*)(Wp1 + off) = *(uint4*)o1;
}

// ---------------------------------------------------------------------------
// Ap buffer 0 (frag order) from initial state. k-blocks: [Ah | Al], K=1024
// ---------------------------------------------------------------------------
__global__ __launch_bounds__(256) void conv_a(const float* __restrict__ S,
                                              f16* __restrict__ Ap)
{
    int p = blockIdx.x * 256 + threadIdx.x;    // (mstrip, kstep, ln)
    const int ln = p & 63; p >>= 6;
    const int kstep = p % AKSTEPS;
    const int strip = p / AKSTEPS;             // 0..15
    const int b = strip * 32 + (ln & 31);
    const int kb0 = kstep * 16 + (ln >> 5) * 8;
    const int blk = kb0 >> 9, bk0 = kb0 & 511;
    f16 out[8];
    #pragma unroll
    for (int j = 0; j < 8; ++j) {
        const int bk = bk0 + j;
        float v = (bk < DD) ? S[(size_t)b * DD + bk] : 0.f;
        f16 hi = (f16)v;
        out[j] = (blk == 1) ? (f16)(v - (float)hi) : hi;
    }
    *(uint4*)(Ap + ((size_t)(strip * AKSTEPS + kstep) * 64 + ln) * 8) = *(uint4*)out;
}

// ---------------------------------------------------------------------------
// Device-wide two-level barrier (once per 8-iter WINDOW only). Monotone,
// relaxed AGENT atomics. bar[g*16] g=0..15 (64B apart), bar[512] root,
// bar[528] generation.
// ---------------------------------------------------------------------------
__device__ __forceinline__ void grid_sync(unsigned* bar, unsigned e)
{
    __syncthreads();
    if (threadIdx.x == 0) {
        unsigned* gcnt = bar + ((blockIdx.x >> 3) << 4);
        unsigned* root = bar + 512;
        unsigned* gen  = bar + 528;
        unsigned a = __hip_atomic_fetch_add(gcnt, 1u, __ATOMIC_RELAXED,
                                            __HIP_MEMORY_SCOPE_AGENT);
        if (a == e * 8u + 7u) {
            unsigned r = __hip_atomic_fetch_add(root, 1u, __ATOMIC_RELAXED,
                                                __HIP_MEMORY_SCOPE_AGENT);
            if (r == e * 16u + 15u) {
                __hip_atomic_store(gen, e + 1u, __ATOMIC_RELAXED,
                                   __HIP_MEMORY_SCOPE_AGENT);
            } else {
                while (__hip_atomic_load(gen, __ATOMIC_RELAXED,
                                         __HIP_MEMORY_SCOPE_AGENT) <= e)
                    __builtin_amdgcn_s_sleep(1);
            }
        } else {
            while (__hip_atomic_load(gen, __ATOMIC_RELAXED,
                                     __HIP_MEMORY_SCOPE_AGENT) <= e)
                __builtin_amdgcn_s_sleep(1);
        }
    }
    __syncthreads();
}

// ---------------------------------------------------------------------------
// Persistent fused kernel. Per iter: stage [Ah|Al] (64 KB) ONCE via asm sc
// 16B loads into LDS | 96-kstep MFMA run (phase3 re-reads Ah from LDS) |
// C->LDS | EW (h in REGISTERS, pack via transient LDS) | asm sc 16B pack
// stores | group signal.  Grid sync + break scan every 8 iters (speculative,
// 8-deep h history ring for the latched output).
// LDS (64KB static, time-multiplexed): A[0,64K) during gemm; then
// Ct[0,36K) + hbufP[40K,48.3K) + red/trig[49.4K).
// ---------------------------------------------------------------------------
__global__ __launch_bounds__(256, 1) void gru_persist(
    f16* __restrict__ ApB,                 // 2 buffers of APCNT
    const f16* __restrict__ Wp0, const f16* __restrict__ Wp1,
    const float* __restrict__ bih, const float* __restrict__ bhh,
    float* __restrict__ out, float* __restrict__ spart,  // [8][64] stride 64
    const float* __restrict__ bc, const int* __restrict__ rec,
    unsigned* __restrict__ bar, unsigned* __restrict__ garr,
    float* __restrict__ hist)
{
    const int bid = blockIdx.x;
    const int tid = threadIdx.x;
    const int rounds = min(64, rec[0]);
    if (rounds <= 0) return;               // uniform: no barriers entered
    const float thr = bc[0] * (float)NELEM;

    const int cg = bid & 7;                // col-group (d base = 64*cg)
    const int mg = bid >> 3;               // row-group = m-strip 0..15
    const int wv = tid >> 6, ln = tid & 63;
    const int sb0 = cg * 8 + 2 * wv, sb1 = sb0 + 1;    // this wave's slabs

    __shared__ __align__(16) char smem[65536];
    f16*      Alds  = (f16*)smem;                      // [64 ks][64 ln][8]
    float*    Ct    = (float*)smem;                    // [32][8][4][9]
    unsigned* hbufP = (unsigned*)(smem + 40960);       // [32][65] hi|lo pack
    float*    red   = (float*)(smem + 49408);
    int*      trig  = (int*)(smem + 49424);

    float h[8];                            // registered h state (own slots)
    #pragma unroll
    for (int i = 0; i < 8; ++i) h[i] = 0.0f;

    f16* bufs0 = ApB;
    f16* bufs1 = ApB + APCNT;
    unsigned* gptr = garr + mg * 16;       // group counter (own 64B line)
    unsigned wep = 0;                      // grid-sync episode

    for (int t = 0; t < rounds; ++t) {
        const f16* Wb   = (t == 0) ? Wp0 : Wp1;
        const f16* Bp0  = Wb + (size_t)sb0 * WKSTEPS * 512 + (size_t)ln * 8;
        const f16* Bp1  = Wb + (size_t)sb1 * WKSTEPS * 512 + (size_t)ln * 8;
        const f16* Asrc = ((t & 1) ? bufs1 : bufs0) + (size_t)mg * AKSTEPS * 512;
        f16*       Apw  = ((t & 1) ? bufs0 : bufs1);   // EW writes other buf

        // B ring prefill (normal cached, XCD-L2-resident; independent of Ap)
        uint4 rB0[12], rB1[12];
        #pragma unroll
        for (int i = 0; i < 12; ++i) {
            rB0[i] = *(const uint4*)(Bp0 + (size_t)i * 512);
            rB1[i] = *(const uint4*)(Bp1 + (size_t)i * 512);
        }
        // group wait: all 8 producers of our A rows finished EW(t-1)
        if (t > 0) {
            if (tid == 0) {
                while (__hip_atomic_load(gptr, __ATOMIC_RELAXED,
                                         __HIP_MEMORY_SCOPE_AGENT)
                       < 8u * (unsigned)t)
                    __builtin_amdgcn_s_sleep(1);
            }
            __syncthreads();
        }

        // stage [Ah|Al] once: 16 x 16B coalesced sc loads per thread
        {
            u32x4 av[16];
            #pragma unroll
            for (int i = 0; i < 16; ++i)
                aload16i(av[i], Asrc + (size_t)(tid + 256 * i) * 8);
            asm volatile("s_waitcnt vmcnt(0)" ::: "memory");
            __builtin_amdgcn_sched_barrier(0);
            #pragma unroll
            for (int i = 0; i < 16; ++i)
                *(u32x4*)(Alds + (size_t)(tid + 256 * i) * 8) = av[i];
        }
        __syncthreads();

        // 96-kstep MFMA run; phase3 (ks>=64: Ah x Wl) re-reads LDS ks-64
        f32x16 acc0 = {}, acc1 = {};
        #pragma unroll
        for (int ks = 0; ks < 96; ++ks) {
            const int kr = (ks < 64) ? ks : (ks - 64);     // compile-time
            f16x8 a = *(const f16x8*)(Alds + (size_t)(kr * 64 + ln) * 8);
            acc0 = __builtin_amdgcn_mfma_f32_32x32x16_f16(
                       a, *(f16x8*)&rB0[ks % 12], acc0, 0, 0, 0);
            acc1 = __builtin_amdgcn_mfma_f32_32x32x16_f16(
                       a, *(f16x8*)&rB1[ks % 12], acc1, 0, 0, 0);
            if (ks < 84) {                 // refill 12 ksteps ahead
                rB0[ks % 12] = *(const uint4*)(Bp0 + (size_t)(ks + 12) * 512);
                rB1[ks % 12] = *(const uint4*)(Bp1 + (size_t)(ks + 12) * 512);
            }
        }
        __syncthreads();                   // all MFMA done before Ct clobbers A

        // C -> LDS. C/D layout: col=lane&31, row=(r&3)+8*(r>>2)+4*(lane>>5).
        // Ct addr = row*288 + sl*36 + g*9 + dd
        {
            const int q = ln & 31, g = q >> 3, dd = q & 7;
            const int sl0 = 2 * wv, sl1 = 2 * wv + 1;
            #pragma unroll
            for (int r = 0; r < 16; ++r) {
                const int row = (r & 3) + 8 * (r >> 2) + 4 * (ln >> 5);
                Ct[row * 288 + sl0 * 36 + g * 9 + dd] = acc0[r];
                Ct[row * 288 + sl1 * 36 + g * 9 + dd] = acc1[r];
            }
        }
        __syncthreads();

        // ---------------- EW phase (h in registers) -----------------------
        float* hw = hist + ((size_t)bid * 8 + (size_t)(t & 7)) * HSTRIDE;
        float psum = 0.0f;
        #pragma unroll
        for (int i = 0; i < 8; ++i) {
            const int idx = i * 256 + tid;     // (row, dl) owned by this thread
            const int row = idx >> 6, dl = idx & 63;
            const int d = cg * 64 + dl;
            const int sl = dl >> 3, dd = dl & 7;
            float hnew = 0.0f;
            if (d < DD) {
                const float* cb = &Ct[row * 288 + sl * 36 + dd];
                float cr = cb[0], cz = cb[9], cin = cb[18], chn = cb[27];
                float r = fsigmoid(cr + bih[d] + bhh[d]);
                float z = fsigmoid(cz + bih[500 + d] + bhh[500 + d]);
                float inn = cin + bih[1000 + d];
                float hn  = bhh[1000 + d];
                float hp  = 0.0f;
                if (t > 0) { hn += chn; hp = h[i]; }
                float n = ftanh(inn + r * hn);
                hnew = (1.0f - z) * n + z * hp;
                psum += hnew;
            }
            h[i] = hnew;
            hw[idx] = hnew;                    // history ring (block-private)
            f16 hi = (f16)hnew;
            f16 lo = (f16)(hnew - (float)hi);
            union { f16 f[2]; unsigned u; } pk;
            pk.f[0] = hi; pk.f[1] = lo;
            hbufP[row * 65 + dl] = pk.u;       // pad-striped: conflict-free
        }
        // block reduce psum -> spart shard cg
        #pragma unroll
        for (int off = 32; off > 0; off >>= 1) psum += __shfl_down(psum, off, 64);
        if (ln == 0) red[wv] = psum;
        __syncthreads();                        // red + hbufP ready
        if (tid == 0) {
            float v = red[0] + red[1] + red[2] + red[3];
            __hip_atomic_fetch_add(&spart[(size_t)cg * 64 + t], v,
                                   __ATOMIC_RELAXED, __HIP_MEMORY_SCOPE_AGENT);
        }
        // pack Ap: thread (lm=tid&31, oct=tid>>5) -> 16B hi @k=d0, lo @512+d0
        // d0 = cg*64 + oct*8  ->  hi kstep = cg*4 + oct/2, lo kstep = 32 + same
        {
            const int lm = tid & 31, oct = tid >> 5;
            union { f16 a[8]; u32x4 v; } hiU, loU;
            #pragma unroll
            for (int j = 0; j < 8; ++j) {
                unsigned u = hbufP[lm * 65 + oct * 8 + j];
                union { unsigned u; f16 f[2]; } pk; pk.u = u;
                hiU.a[j] = pk.f[0];
                loU.a[j] = pk.f[1];
            }
            const int kst = cg * 4 + (oct >> 1), half = oct & 1;   // FIX: +cg*4
            f16* dhi = Apw + ((size_t)(mg * AKSTEPS + kst)      * 64 + half * 32 + lm) * 8;
            f16* dlo = Apw + ((size_t)(mg * AKSTEPS + 32 + kst) * 64 + half * 32 + lm) * 8;
            astore16(dhi, hiU.v);
            astore16(dlo, loU.v);
        }
        asm volatile("s_waitcnt vmcnt(0)" ::: "memory");   // sc stores acked
        __syncthreads();
        if (tid == 0)
            __hip_atomic_fetch_add(gptr, 1u, __ATOMIC_RELAXED,
                                   __HIP_MEMORY_SCOPE_AGENT);

        // -------- window boundary: grid sync + break scan -----------------
        if (((t & 7) == 7) || (t == rounds - 1)) {
            grid_sync(bar, wep++);             // all spart(t' <= t) visible
            if (tid < 64) {                    // wave 0 scans the window
                const int cgl = tid & 7, ti = tid >> 3;
                const int tt = (t & ~7) + ti;
                float v = 0.f;
                if (tt <= t)
                    v = aload_f32(&spart[(size_t)cgl * 64 + tt]);
                v += __shfl_xor(v, 1, 64);
                v += __shfl_xor(v, 2, 64);
                v += __shfl_xor(v, 4, 64);
                bool hit = ((tid & 7) == 0) && (tt <= t) && (v > thr);
                unsigned long long m = __ballot(hit);
                if (tid == 0)
                    trig[0] = m ? (int)((__ffsll((long long)m) - 1) >> 3) : -1;
            }
            __syncthreads();
            const int w0 = trig[0];
            if (w0 >= 0) {                     // break fired at ts (uniform)
                const int ts = (t & ~7) + w0;
                const float* hs = hist
                    + ((size_t)bid * 8 + (size_t)(ts & 7)) * HSTRIDE;
                #pragma unroll
                for (int i = 0; i < 8; ++i) {
                    const int idx = i * 256 + tid;
                    const int row = idx >> 6, dl = idx & 63;
                    const int d = cg * 64 + dl;
                    if (d < DD)
                        out[(size_t)(mg * 32 + row) * DD + d] = hs[idx];
                }
                return;
            }
        }
    }

    // no trigger: final output from registered h
    #pragma unroll
    for (int i = 0; i < 8; ++i) {
        const int idx = i * 256 + tid;
        const int row = idx >> 6, dl = idx & 63;
        const int d = cg * 64 + dl;
        if (d < DD)
            out[(size_t)(mg * 32 + row) * DD + d] = h[i];
    }
}

extern "C" void kernel_launch(void* const* d_in, const int* in_sizes, int n_in,
                              void* d_out, int out_size, void* d_ws, size_t ws_size,
                              hipStream_t stream)
{
    const float* state = (const float*)d_in[0];
    const float* Wih   = (const float*)d_in[1];
    const float* Whh   = (const float*)d_in[2];
    const float* bih   = (const float*)d_in[3];
    const float* bhh   = (const float*)d_in[4];
    const float* bc    = (const float*)d_in[5];
    const int*   rec   = (const int*)d_in[6];

    char* ws = (char*)d_ws;
    float*    spart = (float*)ws;                   // 2 KB (8 shards x 64 t)
    unsigned* bar   = (unsigned*)(ws + 2048);       // 4 KB
    unsigned* garr  = (unsigned*)(ws + 6144);       // 1 KB (16 x 64B)
    f16*   ApB   = (f16*)(ws + 8192);               // 2 x 1 MB
    f16*   Wp0   = ApB + 2 * APCNT;                 // 6.29 MB
    f16*   Wp1   = Wp0 + WPCNT;                     // 6.29 MB
    float* hist  = (float*)(Wp1 + WPCNT);           // 8.39 MB (128x8x2048 f32)
    float* out   = (float*)d_out;

    hipMemsetAsync(ws, 0, 8192, stream);            // spart + bar + garr
    // rec==0 robustness: output = state if no iteration runs
    hipMemcpyAsync(out, state, (size_t)NELEM * sizeof(float),
                   hipMemcpyDeviceToDevice, stream);

    conv_w<<<dim3(NSTRIPS * WKSTEPS * 64 / 256), 256, 0, stream>>>(Wih, Whh, Wp0, Wp1);
    conv_a<<<dim3(MSTRIPS * AKSTEPS * 64 / 256), 256, 0, stream>>>(state, ApB);

    gru_persist<<<dim3(NBLK), dim3(256), 0, stream>>>(
        ApB, Wp0, Wp1, bih, bhh, out, spart, bc, rec, bar, garr, hist);
}

// Round 13
// 803.411 us; speedup vs baseline: 1.6114x; 1.6114x over previous
//
#include <hip/hip_runtime.h>
#include <math.h>
#include <stdint.h>

// Problem constants
#define DD 500
#define BB 512
// Permuted N layout: slab s (0..63) owns cols [32s, 32s+32) = [r|z|i_n|h_n]
// for d in [8s, 8s+8).  r/z cols hold x@(Wih+Whh) for t>=1 (x==h); t=0 uses
// Wp0 (Wih only in r/z).
// Split-precision: C = Ah·Wh + Al·Wh + Ah·Wl.  Wp k-order: [Wh|Wh|Wl]
// (96 ksteps).  Ap holds only [Ah|Al] (64 ksteps, K=1024); the GEMM phase-3
// (ks>=64) re-reads the Ah region from LDS.
#define NSTRIPS 64     // n-strips (slabs) of 32
#define MSTRIPS 16     // m-strips of 32
#define WKSTEPS 96     // Wp ksteps of 16
#define AKSTEPS 64     // Ap ksteps of 16 ([Ah|Al])
#define NELEM (BB*DD)
// Persistent grid: 16 row-groups x 8 col-groups = 128 blocks x 512 threads.
// Block = 32 rows x 256 cols (8 slabs) x full K, 8 waves = slab-pair x K-half
// (per-wave serial B-load chain: 48 ksteps, half of R11's 96).
#define GM 16
#define GN 8
#define NBLK 128
#define HSTRIDE 2048   // floats per (block, hist slot): 32 rows x 64 d

typedef _Float16 f16;
typedef _Float16 f16x8 __attribute__((ext_vector_type(8)));
typedef float    f32x16 __attribute__((ext_vector_type(16)));
typedef unsigned u32x4  __attribute__((ext_vector_type(4)));

#define APCNT ((size_t)MSTRIPS * AKSTEPS * 64 * 8)  // f16 per Ap buffer (1MB)
#define WPCNT ((size_t)NSTRIPS * WKSTEPS * 64 * 8)  // f16 per Wp buffer

// Fragment-order layout (Ap and Wp):
//   elem(strip, kstep, ln, j) at ((strip*KS + kstep)*64 + ln)*8 + j
//   row = strip*32 + (ln&31),  k = kstep*16 + (ln>>5)*8 + j
// = the mfma_f32_32x32x16_f16 A/B operand layout.

__device__ __forceinline__ float aload_f32(const float* p) {
    return __hip_atomic_load(p, __ATOMIC_RELAXED, __HIP_MEMORY_SCOPE_AGENT);
}
// Coalesced device-scope 16B load/store (sc0 sc1: served at the device
// coherence point). Used ONLY with an immediate vmcnt(0) drain (safe:
// no compiler copy can intervene between issue and wait).
__device__ __forceinline__ void aload16i(u32x4& d, const f16* p) {
    asm volatile("global_load_dwordx4 %0, %1, off sc0 sc1"
                 : "=&v"(d) : "v"(p) : "memory");
}
__device__ __forceinline__ void astore16(f16* p, u32x4 v) {
    asm volatile("global_store_dwordx4 %0, %1, off sc0 sc1"
                 :: "v"(p), "v"(v) : "memory");
}

// fast sigmoid/tanh via hardware v_exp: rel err ~1e-6
__device__ __forceinline__ float fsigmoid(float x) {
    return 1.0f / (1.0f + __expf(-x));
}
__device__ __forceinline__ float ftanh(float x) {
    return 2.0f / (1.0f + __expf(-2.0f * x)) - 1.0f;
}

// ---------------------------------------------------------------------------
// Wp0 (t=0) and Wp1 (t>=1), frag order, PERMUTED cols. k-blocks: [Wh|Wh|Wl].
// ---------------------------------------------------------------------------
__global__ __launch_bounds__(256) void conv_w(const float* __restrict__ Wih,
                                              const float* __restrict__ Whh,
                                              f16* __restrict__ Wp0,
                                              f16* __restrict__ Wp1)
{
    int p = blockIdx.x * 256 + threadIdx.x;    // (strip, kstep, ln)
    const int ln = p & 63; p >>= 6;
    const int kstep = p % WKSTEPS;
    const int strip = p / WKSTEPS;             // slab s, 0..63
    const int q = ln & 31;                     // col within slab
    const int g = q >> 3;                      // 0 r, 1 z, 2 i_n, 3 h_n
    const int d = strip * 8 + (q & 7);         // 0..511
    const int kb0 = kstep * 16 + (ln >> 5) * 8;
    const int blk = kb0 >> 9, bk0 = kb0 & 511;
    const float* pih = 0;
    const float* phh = 0;
    if (d < DD) {
        if (g == 0)      { pih = Wih + (size_t)d * DD;
                           phh = Whh + (size_t)d * DD; }
        else if (g == 1) { pih = Wih + (size_t)(500 + d) * DD;
                           phh = Whh + (size_t)(500 + d) * DD; }
        else if (g == 2) { pih = Wih + (size_t)(1000 + d) * DD; }
        else             { phh = Whh + (size_t)(1000 + d) * DD; }
    }
    f16 o0[8], o1[8];
    #pragma unroll
    for (int j = 0; j < 8; ++j) {
        const int bk = bk0 + j;
        float vi = 0.f, vh = 0.f;
        if (bk < DD) {
            if (pih) vi = pih[bk];
            if (phh) vh = phh[bk];
        }
        const float v0 = (g == 3) ? vh : vi;           // Wp0 value
        const float v1 = (g <= 1) ? (vi + vh) : v0;    // Wp1 value
        f16 h0 = (f16)v0;
        f16 h1 = (f16)v1;
        o0[j] = (blk == 2) ? (f16)(v0 - (float)h0) : h0;
        o1[j] = (blk == 2) ? (f16)(v1 - (float)h1) : h1;
    }
    const size_t off = ((size_t)(strip * WKSTEPS + kstep) * 64 + ln) * 8;
    *(uint4*)(Wp0 + off) = *(uint4*)o0;
    *(uint4*)(Wp1 + off) = *(uint4*)o1;
}

// ---------------------------------------------------------------------------
// Ap buffer 0 (frag order) from initial state. k-blocks: [Ah | Al], K=1024
// ---------------------------------------------------------------------------
__global__ __launch_bounds__(256) void conv_a(const float* __restrict__ S,
                                              f16* __restrict__ Ap)
{
    int p = blockIdx.x * 256 + threadIdx.x;    // (mstrip, kstep, ln)
    const int ln = p & 63; p >>= 6;
    const int kstep = p % AKSTEPS;
    const int strip = p / AKSTEPS;             // 0..15
    const int b = strip * 32 + (ln & 31);
    const int kb0 = kstep * 16 + (ln >> 5) * 8;
    const int blk = kb0 >> 9, bk0 = kb0 & 511;
    f16 out[8];
    #pragma unroll
    for (int j = 0; j < 8; ++j) {
        const int bk = bk0 + j;
        float v = (bk < DD) ? S[(size_t)b * DD + bk] : 0.f;
        f16 hi = (f16)v;
        out[j] = (blk == 1) ? (f16)(v - (float)hi) : hi;
    }
    *(uint4*)(Ap + ((size_t)(strip * AKSTEPS + kstep) * 64 + ln) * 8) = *(uint4*)out;
}

// ---------------------------------------------------------------------------
// Device-wide two-level barrier (once per 8-iter WINDOW only). Monotone,
// relaxed AGENT atomics. bar[g*16] g=0..15 (64B apart), bar[512] root,
// bar[528] generation.
// ---------------------------------------------------------------------------
__device__ __forceinline__ void grid_sync(unsigned* bar, unsigned e)
{
    __syncthreads();
    if (threadIdx.x == 0) {
        unsigned* gcnt = bar + ((blockIdx.x >> 3) << 4);
        unsigned* root = bar + 512;
        unsigned* gen  = bar + 528;
        unsigned a = __hip_atomic_fetch_add(gcnt, 1u, __ATOMIC_RELAXED,
                                            __HIP_MEMORY_SCOPE_AGENT);
        if (a == e * 8u + 7u) {
            unsigned r = __hip_atomic_fetch_add(root, 1u, __ATOMIC_RELAXED,
                                                __HIP_MEMORY_SCOPE_AGENT);
            if (r == e * 16u + 15u) {
                __hip_atomic_store(gen, e + 1u, __ATOMIC_RELAXED,
                                   __HIP_MEMORY_SCOPE_AGENT);
            } else {
                while (__hip_atomic_load(gen, __ATOMIC_RELAXED,
                                         __HIP_MEMORY_SCOPE_AGENT) <= e)
                    __builtin_amdgcn_s_sleep(1);
            }
        } else {
            while (__hip_atomic_load(gen, __ATOMIC_RELAXED,
                                     __HIP_MEMORY_SCOPE_AGENT) <= e)
                __builtin_amdgcn_s_sleep(1);
        }
    }
    __syncthreads();
}

// ---------------------------------------------------------------------------
// Persistent fused kernel, 512 threads = 8 waves (slab-pair x K-half).
// Per iter: stage [Ah|Al] (64 KB) once into LDS | 48-kstep MFMA per wave
// (kh=0: ks 0..47, kh=1: ks 48..95; ks>=64 re-reads Ah at ks-64) | Ct
// combine (kh=0 writes, kh=1 adds) | EW (h in registers) | coalesced sc
// pack stores | group signal. Grid sync + break scan every 8 iters.
// LDS 64KB time-multiplexed: Alds during gemm; Ct/hbufP/red/trig after.
// ---------------------------------------------------------------------------
__global__ __launch_bounds__(512, 2) void gru_persist(
    f16* __restrict__ ApB,                 // 2 buffers of APCNT
    const f16* __restrict__ Wp0, const f16* __restrict__ Wp1,
    const float* __restrict__ bih, const float* __restrict__ bhh,
    float* __restrict__ out, float* __restrict__ spart,  // [8][64] stride 64
    const float* __restrict__ bc, const int* __restrict__ rec,
    unsigned* __restrict__ bar, unsigned* __restrict__ garr,
    float* __restrict__ hist)
{
    const int bid = blockIdx.x;
    const int tid = threadIdx.x;
    const int rounds = min(64, rec[0]);
    if (rounds <= 0) return;               // uniform: no barriers entered
    const float thr = bc[0] * (float)NELEM;

    const int cg = bid & 7;                // col-group (d base = 64*cg)
    const int mg = bid >> 3;               // row-group = m-strip 0..15
    const int wv = tid >> 6, ln = tid & 63;
    const int pp = wv & 3;                 // slab-pair 0..3
    const int kh = wv >> 2;                // K-half 0..1
    const int ks0 = kh * 48;               // Wp kstep base for this wave
    const int sb0 = cg * 8 + 2 * pp, sb1 = sb0 + 1;    // global slabs

    __shared__ __align__(16) char smem[65536];
    f16*      Alds  = (f16*)smem;                      // [64 ks][64 ln][8]
    float*    Ct    = (float*)smem;                    // [32][8][4][9]
    unsigned* hbufP = (unsigned*)(smem + 40960);       // [32][65] hi|lo pack
    float*    red   = (float*)(smem + 49408);          // [8]
    int*      trig  = (int*)(smem + 49440);

    float h[4];                            // registered h state (own slots)
    #pragma unroll
    for (int i = 0; i < 4; ++i) h[i] = 0.0f;

    f16* bufs0 = ApB;
    f16* bufs1 = ApB + APCNT;
    unsigned* gptr = garr + mg * 16;       // group counter (own 64B line)
    unsigned wep = 0;                      // grid-sync episode

    for (int t = 0; t < rounds; ++t) {
        const f16* Wb   = (t == 0) ? Wp0 : Wp1;
        const f16* Bp0  = Wb + (size_t)(sb0 * WKSTEPS + ks0) * 512 + (size_t)ln * 8;
        const f16* Bp1  = Wb + (size_t)(sb1 * WKSTEPS + ks0) * 512 + (size_t)ln * 8;
        const f16* Asrc = ((t & 1) ? bufs1 : bufs0) + (size_t)mg * AKSTEPS * 512;
        f16*       Apw  = ((t & 1) ? bufs0 : bufs1);   // EW writes other buf

        // B ring prefill (normal cached, XCD-L2-resident; independent of Ap)
        uint4 rB0[12], rB1[12];
        #pragma unroll
        for (int i = 0; i < 12; ++i) {
            rB0[i] = *(const uint4*)(Bp0 + (size_t)i * 512);
            rB1[i] = *(const uint4*)(Bp1 + (size_t)i * 512);
        }
        // group wait: all 8 producers of our A rows finished EW(t-1)
        if (t > 0) {
            if (tid == 0) {
                while (__hip_atomic_load(gptr, __ATOMIC_RELAXED,
                                         __HIP_MEMORY_SCOPE_AGENT)
                       < 8u * (unsigned)t)
                    __builtin_amdgcn_s_sleep(1);
            }
            __syncthreads();
        }

        // stage [Ah|Al] once: 8 x 16B coalesced sc loads per thread (512 thr)
        {
            u32x4 av[8];
            #pragma unroll
            for (int i = 0; i < 8; ++i)
                aload16i(av[i], Asrc + (size_t)(tid + 512 * i) * 8);
            asm volatile("s_waitcnt vmcnt(0)" ::: "memory");  // drains prefill too
            __builtin_amdgcn_sched_barrier(0);
            #pragma unroll
            for (int i = 0; i < 8; ++i)
                *(u32x4*)(Alds + (size_t)(tid + 512 * i) * 8) = av[i];
        }
        __syncthreads();

        // 48-kstep MFMA run (this wave's K-half); ks>=64 re-reads Ah at ks-64
        f32x16 acc0 = {}, acc1 = {};
        #pragma unroll
        for (int ksl = 0; ksl < 48; ++ksl) {
            const int ks = ks0 + ksl;                       // kh const per wave
            const int kr = (ks < 64) ? ks : (ks - 64);      // compile-time-ish
            f16x8 a = *(const f16x8*)(Alds + (size_t)(kr * 64 + ln) * 8);
            acc0 = __builtin_amdgcn_mfma_f32_32x32x16_f16(
                       a, *(f16x8*)&rB0[ksl % 12], acc0, 0, 0, 0);
            acc1 = __builtin_amdgcn_mfma_f32_32x32x16_f16(
                       a, *(f16x8*)&rB1[ksl % 12], acc1, 0, 0, 0);
            if (ksl < 36) {                // refill ring slot 12 ahead
                rB0[ksl % 12] = *(const uint4*)(Bp0 + (size_t)(ksl + 12) * 512);
                rB1[ksl % 12] = *(const uint4*)(Bp1 + (size_t)(ksl + 12) * 512);
            }
        }
        __syncthreads();                   // all MFMA done before Ct clobbers A

        // Ct combine. C/D layout: col=lane&31, row=(r&3)+8*(r>>2)+4*(lane>>5)
        // Ct addr = row*288 + sl*36 + g*9 + dd.  kh=0 writes, kh=1 adds.
        {
            const int q = ln & 31, g = q >> 3, dd = q & 7;
            const int sl0 = 2 * pp, sl1 = 2 * pp + 1;
            if (kh == 0) {
                #pragma unroll
                for (int r = 0; r < 16; ++r) {
                    const int row = (r & 3) + 8 * (r >> 2) + 4 * (ln >> 5);
                    Ct[row * 288 + sl0 * 36 + g * 9 + dd] = acc0[r];
                    Ct[row * 288 + sl1 * 36 + g * 9 + dd] = acc1[r];
                }
            }
            __syncthreads();
            if (kh == 1) {
                #pragma unroll
                for (int r = 0; r < 16; ++r) {
                    const int row = (r & 3) + 8 * (r >> 2) + 4 * (ln >> 5);
                    Ct[row * 288 + sl0 * 36 + g * 9 + dd] += acc0[r];
                    Ct[row * 288 + sl1 * 36 + g * 9 + dd] += acc1[r];
                }
            }
            __syncthreads();
        }

        // ---------------- EW phase (h in registers) -----------------------
        float* hw = hist + ((size_t)bid * 8 + (size_t)(t & 7)) * HSTRIDE;
        float psum = 0.0f;
        #pragma unroll
        for (int i = 0; i < 4; ++i) {
            const int idx = i * 512 + tid;     // (row, dl) owned by this thread
            const int row = idx >> 6, dl = idx & 63;
            const int d = cg * 64 + dl;
            const int sl = dl >> 3, dd = dl & 7;
            float hnew = 0.0f;
            if (d < DD) {
                const float* cb = &Ct[row * 288 + sl * 36 + dd];
                float cr = cb[0], cz = cb[9], cin = cb[18], chn = cb[27];
                float r = fsigmoid(cr + bih[d] + bhh[d]);
                float z = fsigmoid(cz + bih[500 + d] + bhh[500 + d]);
                float inn = cin + bih[1000 + d];
                float hn  = bhh[1000 + d];
                float hp  = 0.0f;
                if (t > 0) { hn += chn; hp = h[i]; }
                float n = ftanh(inn + r * hn);
                hnew = (1.0f - z) * n + z * hp;
                psum += hnew;
            }
            h[i] = hnew;
            hw[idx] = hnew;                    // history ring (block-private)
            f16 hi = (f16)hnew;
            f16 lo = (f16)(hnew - (float)hi);
            union { f16 f[2]; unsigned u; } pk;
            pk.f[0] = hi; pk.f[1] = lo;
            hbufP[row * 65 + dl] = pk.u;       // pad-striped: conflict-free
        }
        // block reduce psum -> spart shard cg
        #pragma unroll
        for (int off = 32; off > 0; off >>= 1) psum += __shfl_down(psum, off, 64);
        if (ln == 0) red[wv] = psum;
        __syncthreads();                        // red + hbufP ready
        if (tid == 0) {
            float v = red[0] + red[1] + red[2] + red[3]
                    + red[4] + red[5] + red[6] + red[7];
            __hip_atomic_fetch_add(&spart[(size_t)cg * 64 + t], v,
                                   __ATOMIC_RELAXED, __HIP_MEMORY_SCOPE_AGENT);
        }
        // pack Ap: thread (lm=tid&31, oct=tid>>5) -> 16B hi @k=d0, lo @512+d0
        // d0 = cg*64 + oct*8  ->  hi kstep = cg*4 + oct/2, lo kstep = 32 + same
        if (tid < 256) {
            const int lm = tid & 31, oct = tid >> 5;
            union { f16 a[8]; u32x4 v; } hiU, loU;
            #pragma unroll
            for (int j = 0; j < 8; ++j) {
                unsigned u = hbufP[lm * 65 + oct * 8 + j];
                union { unsigned u; f16 f[2]; } pk; pk.u = u;
                hiU.a[j] = pk.f[0];
                loU.a[j] = pk.f[1];
            }
            const int kst = cg * 4 + (oct >> 1), half = oct & 1;
            f16* dhi = Apw + ((size_t)(mg * AKSTEPS + kst)      * 64 + half * 32 + lm) * 8;
            f16* dlo = Apw + ((size_t)(mg * AKSTEPS + 32 + kst) * 64 + half * 32 + lm) * 8;
            astore16(dhi, hiU.v);
            astore16(dlo, loU.v);
        }
        asm volatile("s_waitcnt vmcnt(0)" ::: "memory");   // sc stores acked
        __syncthreads();
        if (tid == 0)
            __hip_atomic_fetch_add(gptr, 1u, __ATOMIC_RELAXED,
                                   __HIP_MEMORY_SCOPE_AGENT);

        // -------- window boundary: grid sync + break scan -----------------
        if (((t & 7) == 7) || (t == rounds - 1)) {
            grid_sync(bar, wep++);             // all spart(t' <= t) visible
            if (tid < 64) {                    // wave 0 scans the window
                const int cgl = tid & 7, ti = tid >> 3;
                const int tt = (t & ~7) + ti;
                float v = 0.f;
                if (tt <= t)
                    v = aload_f32(&spart[(size_t)cgl * 64 + tt]);
                v += __shfl_xor(v, 1, 64);
                v += __shfl_xor(v, 2, 64);
                v += __shfl_xor(v, 4, 64);
                bool hit = ((tid & 7) == 0) && (tt <= t) && (v > thr);
                unsigned long long m = __ballot(hit);
                if (tid == 0)
                    trig[0] = m ? (int)((__ffsll((long long)m) - 1) >> 3) : -1;
            }
            __syncthreads();
            const int w0 = trig[0];
            if (w0 >= 0) {                     // break fired at ts (uniform)
                const int ts = (t & ~7) + w0;
                const float* hs = hist
                    + ((size_t)bid * 8 + (size_t)(ts & 7)) * HSTRIDE;
                #pragma unroll
                for (int i = 0; i < 4; ++i) {
                    const int idx = i * 512 + tid;
                    const int row = idx >> 6, dl = idx & 63;
                    const int d = cg * 64 + dl;
                    if (d < DD)
                        out[(size_t)(mg * 32 + row) * DD + d] = hs[idx];
                }
                return;
            }
        }
    }

    // no trigger: final output from registered h
    #pragma unroll
    for (int i = 0; i < 4; ++i) {
        const int idx = i * 512 + tid;
        const int row = idx >> 6, dl = idx & 63;
        const int d = cg * 64 + dl;
        if (d < DD)
            out[(size_t)(mg * 32 + row) * DD + d] = h[i];
    }
}

extern "C" void kernel_launch(void* const* d_in, const int* in_sizes, int n_in,
                              void* d_out, int out_size, void* d_ws, size_t ws_size,
                              hipStream_t stream)
{
    const float* state = (const float*)d_in[0];
    const float* Wih   = (const float*)d_in[1];
    const float* Whh   = (const float*)d_in[2];
    const float* bih   = (const float*)d_in[3];
    const float* bhh   = (const float*)d_in[4];
    const float* bc    = (const float*)d_in[5];
    const int*   rec   = (const int*)d_in[6];

    char* ws = (char*)d_ws;
    float*    spart = (float*)ws;                   // 2 KB (8 shards x 64 t)
    unsigned* bar   = (unsigned*)(ws + 2048);       // 4 KB
    unsigned* garr  = (unsigned*)(ws + 6144);       // 1 KB (16 x 64B)
    f16*   ApB   = (f16*)(ws + 8192);               // 2 x 1 MB
    f16*   Wp0   = ApB + 2 * APCNT;                 // 6.29 MB
    f16*   Wp1   = Wp0 + WPCNT;                     // 6.29 MB
    float* hist  = (float*)(Wp1 + WPCNT);           // 8.39 MB (128x8x2048 f32)
    float* out   = (float*)d_out;

    hipMemsetAsync(ws, 0, 8192, stream);            // spart + bar + garr
    // rec==0 robustness: output = state if no iteration runs
    hipMemcpyAsync(out, state, (size_t)NELEM * sizeof(float),
                   hipMemcpyDeviceToDevice, stream);

    conv_w<<<dim3(NSTRIPS * WKSTEPS * 64 / 256), 256, 0, stream>>>(Wih, Whh, Wp0, Wp1);
    conv_a<<<dim3(MSTRIPS * AKSTEPS * 64 / 256), 256, 0, stream>>>(state, ApB);

    gru_persist<<<dim3(NBLK), dim3(512), 0, stream>>>(
        ApB, Wp0, Wp1, bih, bhh, out, spart, bc, rec, bar, garr, hist);
}

// Round 14
// 689.432 us; speedup vs baseline: 1.8778x; 1.1653x over previous
//
#include <hip/hip_runtime.h>
#include <math.h>
#include <stdint.h>

// Problem constants
#define DD 500
#define BB 512
// Permuted N layout: slab s (0..63) owns cols [32s, 32s+32) = [r|z|i_n|h_n]
// for d in [8s, 8s+8).  r/z cols hold x@(Wih+Whh) for t>=1 (x==h); t=0 uses
// Wp0 (Wih only in r/z).
// Split-precision: C = Ah·Wh + Al·Wh + Ah·Wl.  Wp k-order: [Wh|Wh|Wl]
// (wksteps 0..31 Wh(x Ah), 32..63 Wh(x Al), 64..95 Wl(x Ah)).
// Ap holds [Ah|Al] (64 ksteps, K=1024).
#define NSTRIPS 64     // n-strips (slabs) of 32
#define MSTRIPS 16     // m-strips of 32
#define WKSTEPS 96     // Wp ksteps of 16
#define AKSTEPS 64     // Ap ksteps of 16 ([Ah|Al])
#define NELEM (BB*DD)
// Persistent grid: 8 row-groups (64 rows) x 32 col-groups (2 slabs, 16 d)
// = 256 blocks x 512 threads = ALL 256 CUs. bid%8 = cg%8 -> blocks sharing a
// B slice land on one XCD (786KB Wp slice per XCD L2).
// B volume/iter: (512/64) x 6.3MB = 50MB (half of R13). Per-wave chain:
// 24 ksteps (8 waves = m-half x K-quarter).
#define GRG 8
#define GCG 32
#define NBLK 256
#define HSTRIDE 1024   // floats per (block, hist slot): 64 rows x 16 d

typedef _Float16 f16;
typedef _Float16 f16x8 __attribute__((ext_vector_type(8)));
typedef float    f32x16 __attribute__((ext_vector_type(16)));
typedef unsigned u32x4  __attribute__((ext_vector_type(4)));

#define APCNT ((size_t)MSTRIPS * AKSTEPS * 64 * 8)  // f16 per Ap buffer (1MB)
#define WPCNT ((size_t)NSTRIPS * WKSTEPS * 64 * 8)  // f16 per Wp buffer

// Fragment-order layout (Ap and Wp):
//   elem(strip, kstep, ln, j) at ((strip*KS + kstep)*64 + ln)*8 + j
//   row = strip*32 + (ln&31),  k = kstep*16 + (ln>>5)*8 + j
// = the mfma_f32_32x32x16_f16 A/B operand layout.

__device__ __forceinline__ float aload_f32(const float* p) {
    return __hip_atomic_load(p, __ATOMIC_RELAXED, __HIP_MEMORY_SCOPE_AGENT);
}
// Coalesced device-scope 16B load/store (sc0 sc1: served at the device
// coherence point). Used ONLY with an immediate vmcnt(0) drain.
__device__ __forceinline__ void aload16i(u32x4& d, const f16* p) {
    asm volatile("global_load_dwordx4 %0, %1, off sc0 sc1"
                 : "=&v"(d) : "v"(p) : "memory");
}
__device__ __forceinline__ void astore16(f16* p, u32x4 v) {
    asm volatile("global_store_dwordx4 %0, %1, off sc0 sc1"
                 :: "v"(p), "v"(v) : "memory");
}

// fast sigmoid/tanh via hardware v_exp: rel err ~1e-6
__device__ __forceinline__ float fsigmoid(float x) {
    return 1.0f / (1.0f + __expf(-x));
}
__device__ __forceinline__ float ftanh(float x) {
    return 2.0f / (1.0f + __expf(-2.0f * x)) - 1.0f;
}

// ---------------------------------------------------------------------------
// Wp0 (t=0) and Wp1 (t>=1), frag order, PERMUTED cols. k-blocks: [Wh|Wh|Wl].
// ---------------------------------------------------------------------------
__global__ __launch_bounds__(256) void conv_w(const float* __restrict__ Wih,
                                              const float* __restrict__ Whh,
                                              f16* __restrict__ Wp0,
                                              f16* __restrict__ Wp1)
{
    int p = blockIdx.x * 256 + threadIdx.x;    // (strip, kstep, ln)
    const int ln = p & 63; p >>= 6;
    const int kstep = p % WKSTEPS;
    const int strip = p / WKSTEPS;             // slab s, 0..63
    const int q = ln & 31;                     // col within slab
    const int g = q >> 3;                      // 0 r, 1 z, 2 i_n, 3 h_n
    const int d = strip * 8 + (q & 7);         // 0..511
    const int kb0 = kstep * 16 + (ln >> 5) * 8;
    const int blk = kb0 >> 9, bk0 = kb0 & 511;
    const float* pih = 0;
    const float* phh = 0;
    if (d < DD) {
        if (g == 0)      { pih = Wih + (size_t)d * DD;
                           phh = Whh + (size_t)d * DD; }
        else if (g == 1) { pih = Wih + (size_t)(500 + d) * DD;
                           phh = Whh + (size_t)(500 + d) * DD; }
        else if (g == 2) { pih = Wih + (size_t)(1000 + d) * DD; }
        else             { phh = Whh + (size_t)(1000 + d) * DD; }
    }
    f16 o0[8], o1[8];
    #pragma unroll
    for (int j = 0; j < 8; ++j) {
        const int bk = bk0 + j;
        float vi = 0.f, vh = 0.f;
        if (bk < DD) {
            if (pih) vi = pih[bk];
            if (phh) vh = phh[bk];
        }
        const float v0 = (g == 3) ? vh : vi;           // Wp0 value
        const float v1 = (g <= 1) ? (vi + vh) : v0;    // Wp1 value
        f16 h0 = (f16)v0;
        f16 h1 = (f16)v1;
        o0[j] = (blk == 2) ? (f16)(v0 - (float)h0) : h0;
        o1[j] = (blk == 2) ? (f16)(v1 - (float)h1) : h1;
    }
    const size_t off = ((size_t)(strip * WKSTEPS + kstep) * 64 + ln) * 8;
    *(uint4*)(Wp0 + off) = *(uint4*)o0;
    *(uint4*)(Wp1 + off) = *(uint4*)o1;
}

// ---------------------------------------------------------------------------
// Ap buffer 0 (frag order) from initial state. k-blocks: [Ah | Al], K=1024
// ---------------------------------------------------------------------------
__global__ __launch_bounds__(256) void conv_a(const float* __restrict__ S,
                                              f16* __restrict__ Ap)
{
    int p = blockIdx.x * 256 + threadIdx.x;    // (mstrip, kstep, ln)
    const int ln = p & 63; p >>= 6;
    const int kstep = p % AKSTEPS;
    const int strip = p / AKSTEPS;             // 0..15
    const int b = strip * 32 + (ln & 31);
    const int kb0 = kstep * 16 + (ln >> 5) * 8;
    const int blk = kb0 >> 9, bk0 = kb0 & 511;
    f16 out[8];
    #pragma unroll
    for (int j = 0; j < 8; ++j) {
        const int bk = bk0 + j;
        float v = (bk < DD) ? S[(size_t)b * DD + bk] : 0.f;
        f16 hi = (f16)v;
        out[j] = (blk == 1) ? (f16)(v - (float)hi) : hi;
    }
    *(uint4*)(Ap + ((size_t)(strip * AKSTEPS + kstep) * 64 + ln) * 8) = *(uint4*)out;
}

// ---------------------------------------------------------------------------
// Device-wide two-level barrier (once per 8-iter WINDOW only). Monotone,
// relaxed AGENT atomics. 32 groups of 8 blocks: bar[g*16] (64B apart),
// bar[512] root (32 arrivals), bar[528] generation.
// ---------------------------------------------------------------------------
__device__ __forceinline__ void grid_sync(unsigned* bar, unsigned e)
{
    __syncthreads();
    if (threadIdx.x == 0) {
        unsigned* gcnt = bar + ((blockIdx.x >> 3) << 4);
        unsigned* root = bar + 512;
        unsigned* gen  = bar + 528;
        unsigned a = __hip_atomic_fetch_add(gcnt, 1u, __ATOMIC_RELAXED,
                                            __HIP_MEMORY_SCOPE_AGENT);
        if (a == e * 8u + 7u) {
            unsigned r = __hip_atomic_fetch_add(root, 1u, __ATOMIC_RELAXED,
                                                __HIP_MEMORY_SCOPE_AGENT);
            if (r == e * 32u + 31u) {
                __hip_atomic_store(gen, e + 1u, __ATOMIC_RELAXED,
                                   __HIP_MEMORY_SCOPE_AGENT);
            } else {
                while (__hip_atomic_load(gen, __ATOMIC_RELAXED,
                                         __HIP_MEMORY_SCOPE_AGENT) <= e)
                    __builtin_amdgcn_s_sleep(1);
            }
        } else {
            while (__hip_atomic_load(gen, __ATOMIC_RELAXED,
                                     __HIP_MEMORY_SCOPE_AGENT) <= e)
                __builtin_amdgcn_s_sleep(1);
        }
    }
    __syncthreads();
}

// ---------------------------------------------------------------------------
// Persistent fused kernel, 256 blocks x 512 threads (8 waves = m-half x
// K-quarter). Block = 64 rows x 2 slabs x full K.
// Per iter: prefill B ring | group wait | stage Ah chunk (64KB) + issue Al
// loads early | phase-H MFMA (wk in {kq*8..}+{64+kq*8..}, 16 ksteps/wave) |
// restage Al | phase-L MFMA (8 ksteps/wave) | Ct 4-round kq combine | EW
// (h in regs) | pack (coalesced sc stores) | group signal. Grid sync +
// break scan every 8 iters (speculative, 8-deep h history ring).
// LDS 64KB time-multiplexed: A chunk during gemm; Ct[64][72] + hbufP +
// red/trig after (A dead).
// ---------------------------------------------------------------------------
__global__ __launch_bounds__(512, 2) void gru_persist(
    f16* __restrict__ ApB,                 // 2 buffers of APCNT
    const f16* __restrict__ Wp0, const f16* __restrict__ Wp1,
    const float* __restrict__ bih, const float* __restrict__ bhh,
    float* __restrict__ out, float* __restrict__ spart,  // [8][64] stride 64
    const float* __restrict__ bc, const int* __restrict__ rec,
    unsigned* __restrict__ bar, unsigned* __restrict__ garr,
    float* __restrict__ hist)
{
    const int bid = blockIdx.x;
    const int tid = threadIdx.x;
    const int rounds = min(64, rec[0]);
    if (rounds <= 0) return;               // uniform: no barriers entered
    const float thr = bc[0] * (float)NELEM;

    const int cg = bid & 31;               // col-group (d base = 16*cg)
    const int rg = bid >> 5;               // row-group (64 rows)
    const int wv = tid >> 6, ln = tid & 63;
    const int mh = wv >> 2;                // m-half (32 rows)
    const int kq = wv & 3;                 // K-quarter
    const int sb0 = cg * 2, sb1 = cg * 2 + 1;          // this block's slabs

    __shared__ __align__(16) char smem[65536];
    f16*      Alds  = (f16*)smem;                      // [2 sl][32 aks][64][8]
    float*    Ct    = (float*)smem;                    // [64][2 sl][4 g][9]
    unsigned* hbufP = (unsigned*)(smem + 20480);       // [64][17] hi|lo pack
    float*    red   = (float*)(smem + 24832);          // [8]
    int*      trig  = (int*)(smem + 24864);

    float h[2];                            // registered h state (own slots)
    h[0] = 0.0f; h[1] = 0.0f;

    f16* bufs0 = ApB;
    f16* bufs1 = ApB + APCNT;
    unsigned* gptr = garr + rg * 16;       // group counter (own 64B line)
    unsigned wep = 0;                      // grid-sync episode

    for (int t = 0; t < rounds; ++t) {
        const f16* Wb    = (t == 0) ? Wp0 : Wp1;
        const f16* Abase = (t & 1) ? bufs1 : bufs0;
        f16*       Apw   = (t & 1) ? bufs0 : bufs1;    // EW writes other buf
        const f16* Bb0   = Wb + (size_t)sb0 * WKSTEPS * 512 + (size_t)ln * 8;
        const f16* Bb1   = Wb + (size_t)sb1 * WKSTEPS * 512 + (size_t)ln * 8;

        // phase-H B ring prefill: wk = kq*8 + i (independent of Ap)
        uint4 rB0[8], rB1[8];
        #pragma unroll
        for (int i = 0; i < 8; ++i) {
            rB0[i] = *(const uint4*)(Bb0 + (size_t)(kq * 8 + i) * 512);
            rB1[i] = *(const uint4*)(Bb1 + (size_t)(kq * 8 + i) * 512);
        }
        // group wait: all 32 producers of our A rows finished EW(t-1)
        if (t > 0) {
            if (tid == 0) {
                while (__hip_atomic_load(gptr, __ATOMIC_RELAXED,
                                         __HIP_MEMORY_SCOPE_AGENT)
                       < 32u * (unsigned)t)
                    __builtin_amdgcn_s_sleep(1);
            }
            __syncthreads();
        }

        // stage chunk H (Ah: aks 0..31, strips 2rg,2rg+1): 8 x 16B sc / thr
        u32x4 av[8];
        #pragma unroll
        for (int i = 0; i < 8; ++i) {
            const int flat = tid + 512 * i;
            const int sl_ = flat >> 11, rem = flat & 2047;
            aload16i(av[i], Abase +
                ((size_t)((2 * rg + sl_) * AKSTEPS + (rem >> 6)) * 64
                 + (rem & 63)) * 8);
        }
        asm volatile("s_waitcnt vmcnt(0)" ::: "memory");
        __builtin_amdgcn_sched_barrier(0);
        #pragma unroll
        for (int i = 0; i < 8; ++i)
            *(u32x4*)(Alds + (size_t)(tid + 512 * i) * 8) = av[i];
        // issue chunk L (Al: aks 32..63) loads NOW: latency hides under
        // phase-H MFMA (registers held across the phase)
        #pragma unroll
        for (int i = 0; i < 8; ++i) {
            const int flat = tid + 512 * i;
            const int sl_ = flat >> 11, rem = flat & 2047;
            aload16i(av[i], Abase +
                ((size_t)((2 * rg + sl_) * AKSTEPS + 32 + (rem >> 6)) * 64
                 + (rem & 63)) * 8);
        }
        __syncthreads();

        // phase H: 16 ksteps/wave. wk = kq*8+ksl (ksl<8) or 64+kq*8+(ksl-8);
        // A kstep ka = kq*8 + (ksl&7) in both (Ah pairs with Wh and Wl).
        f32x16 acc0 = {}, acc1 = {};
        #pragma unroll
        for (int ksl = 0; ksl < 16; ++ksl) {
            const int ka = kq * 8 + (ksl & 7);
            f16x8 a = *(const f16x8*)(Alds + ((size_t)(mh * 32 + ka) * 512
                                              + (size_t)ln * 8));
            acc0 = __builtin_amdgcn_mfma_f32_32x32x16_f16(
                       a, *(f16x8*)&rB0[ksl & 7], acc0, 0, 0, 0);
            acc1 = __builtin_amdgcn_mfma_f32_32x32x16_f16(
                       a, *(f16x8*)&rB1[ksl & 7], acc1, 0, 0, 0);
            if (ksl < 8) {                 // refill slot ksl with wk=64+kq*8+ksl
                rB0[ksl] = *(const uint4*)(Bb0 + (size_t)(64 + kq * 8 + ksl) * 512);
                rB1[ksl] = *(const uint4*)(Bb1 + (size_t)(64 + kq * 8 + ksl) * 512);
            }
        }
        __syncthreads();                   // phase-H A reads done

        // restage chunk L into the same buffer
        asm volatile("s_waitcnt vmcnt(0)" ::: "memory");
        __builtin_amdgcn_sched_barrier(0);
        #pragma unroll
        for (int i = 0; i < 8; ++i)
            *(u32x4*)(Alds + (size_t)(tid + 512 * i) * 8) = av[i];
        // phase-L B ring prefill: wk = 32 + kq*8 + i
        #pragma unroll
        for (int i = 0; i < 8; ++i) {
            rB0[i] = *(const uint4*)(Bb0 + (size_t)(32 + kq * 8 + i) * 512);
            rB1[i] = *(const uint4*)(Bb1 + (size_t)(32 + kq * 8 + i) * 512);
        }
        __syncthreads();

        // phase L: 8 ksteps/wave (Al x Wh)
        #pragma unroll
        for (int ksl = 0; ksl < 8; ++ksl) {
            const int ka = kq * 8 + ksl;
            f16x8 a = *(const f16x8*)(Alds + ((size_t)(mh * 32 + ka) * 512
                                              + (size_t)ln * 8));
            acc0 = __builtin_amdgcn_mfma_f32_32x32x16_f16(
                       a, *(f16x8*)&rB0[ksl], acc0, 0, 0, 0);
            acc1 = __builtin_amdgcn_mfma_f32_32x32x16_f16(
                       a, *(f16x8*)&rB1[ksl], acc1, 0, 0, 0);
        }
        __syncthreads();                   // all MFMA done; A buffer dead

        // Ct combine, 4 serialized kq rounds. C/D layout: col=lane&31,
        // row=(r&3)+8*(r>>2)+4*(lane>>5). Ct addr = row*72 + sl*36 + g*9 + dd
        {
            const int q = ln & 31, g = q >> 3, dd = q & 7;
            #pragma unroll
            for (int k = 0; k < 4; ++k) {
                if (kq == k) {
                    #pragma unroll
                    for (int r = 0; r < 16; ++r) {
                        const int row = mh * 32 + (r & 3) + 8 * (r >> 2)
                                        + 4 * (ln >> 5);
                        float* c0 = Ct + row * 72 + g * 9 + dd;
                        float* c1 = c0 + 36;
                        if (k == 0) { *c0 = acc0[r];  *c1 = acc1[r]; }
                        else        { *c0 += acc0[r]; *c1 += acc1[r]; }
                    }
                }
                __syncthreads();
            }
        }

        // ---------------- EW phase (h in registers) -----------------------
        float* hw = hist + ((size_t)bid * 8 + (size_t)(t & 7)) * HSTRIDE;
        float psum = 0.0f;
        #pragma unroll
        for (int i = 0; i < 2; ++i) {
            const int idx = i * 512 + tid;     // 1024 (row, dl) pairs
            const int row = idx >> 4, dl = idx & 15;
            const int d = cg * 16 + dl;
            const int sl = dl >> 3, dd = dl & 7;
            float hnew = 0.0f;
            if (d < DD) {
                const float* cb = &Ct[row * 72 + sl * 36 + dd];
                float cr = cb[0], cz = cb[9], cin = cb[18], chn = cb[27];
                float r = fsigmoid(cr + bih[d] + bhh[d]);
                float z = fsigmoid(cz + bih[500 + d] + bhh[500 + d]);
                float inn = cin + bih[1000 + d];
                float hn  = bhh[1000 + d];
                float hp  = 0.0f;
                if (t > 0) { hn += chn; hp = h[i]; }
                float n = ftanh(inn + r * hn);
                hnew = (1.0f - z) * n + z * hp;
                psum += hnew;
            }
            h[i] = hnew;
            hw[idx] = hnew;                    // history ring (block-private)
            f16 hi = (f16)hnew;
            f16 lo = (f16)(hnew - (float)hi);
            union { f16 f[2]; unsigned u; } pk;
            pk.f[0] = hi; pk.f[1] = lo;
            hbufP[row * 17 + dl] = pk.u;       // pad-striped
        }
        // block reduce psum -> spart shard (cg&7)
        #pragma unroll
        for (int off = 32; off > 0; off >>= 1) psum += __shfl_down(psum, off, 64);
        if (ln == 0) red[wv] = psum;
        __syncthreads();                        // red + hbufP ready
        if (tid == 0) {
            float v = red[0] + red[1] + red[2] + red[3]
                    + red[4] + red[5] + red[6] + red[7];
            __hip_atomic_fetch_add(&spart[(size_t)(cg & 7) * 64 + t], v,
                                   __ATOMIC_RELAXED, __HIP_MEMORY_SCOPE_AGENT);
        }
        // pack Ap: (row 0..63, oct 0..1) -> d0 = cg*16 + oct*8.
        // hi kstep = cg, lo kstep = 32+cg, half = oct, strip = 2rg + row/32.
        if (tid < 128) {
            const int row = tid >> 1, oct = tid & 1;
            union { f16 a[8]; u32x4 v; } hiU, loU;
            #pragma unroll
            for (int j = 0; j < 8; ++j) {
                unsigned u = hbufP[row * 17 + oct * 8 + j];
                union { unsigned u; f16 f[2]; } pk; pk.u = u;
                hiU.a[j] = pk.f[0];
                loU.a[j] = pk.f[1];
            }
            const int strip = 2 * rg + (row >> 5), lm = row & 31;
            f16* dhi = Apw + ((size_t)(strip * AKSTEPS + cg)      * 64
                              + oct * 32 + lm) * 8;
            f16* dlo = Apw + ((size_t)(strip * AKSTEPS + 32 + cg) * 64
                              + oct * 32 + lm) * 8;
            astore16(dhi, hiU.v);
            astore16(dlo, loU.v);
        }
        asm volatile("s_waitcnt vmcnt(0)" ::: "memory");   // sc stores acked
        __syncthreads();
        if (tid == 0)
            __hip_atomic_fetch_add(gptr, 1u, __ATOMIC_RELAXED,
                                   __HIP_MEMORY_SCOPE_AGENT);

        // -------- window boundary: grid sync + break scan -----------------
        if (((t & 7) == 7) || (t == rounds - 1)) {
            grid_sync(bar, wep++);             // all spart(t' <= t) visible
            if (tid < 64) {                    // wave 0 scans the window
                const int cgl = tid & 7, ti = tid >> 3;
                const int tt = (t & ~7) + ti;
                float v = 0.f;
                if (tt <= t)
                    v = aload_f32(&spart[(size_t)cgl * 64 + tt]);
                v += __shfl_xor(v, 1, 64);
                v += __shfl_xor(v, 2, 64);
                v += __shfl_xor(v, 4, 64);
                bool hit = ((tid & 7) == 0) && (tt <= t) && (v > thr);
                unsigned long long m = __ballot(hit);
                if (tid == 0)
                    trig[0] = m ? (int)((__ffsll((long long)m) - 1) >> 3) : -1;
            }
            __syncthreads();
            const int w0 = trig[0];
            if (w0 >= 0) {                     // break fired at ts (uniform)
                const int ts = (t & ~7) + w0;
                const float* hs = hist
                    + ((size_t)bid * 8 + (size_t)(ts & 7)) * HSTRIDE;
                #pragma unroll
                for (int i = 0; i < 2; ++i) {
                    const int idx = i * 512 + tid;
                    const int row = idx >> 4, dl = idx & 15;
                    const int d = cg * 16 + dl;
                    if (d < DD)
                        out[(size_t)(rg * 64 + row) * DD + d] = hs[idx];
                }
                return;
            }
        }
    }

    // no trigger: final output from registered h
    #pragma unroll
    for (int i = 0; i < 2; ++i) {
        const int idx = i * 512 + tid;
        const int row = idx >> 4, dl = idx & 15;
        const int d = cg * 16 + dl;
        if (d < DD)
            out[(size_t)(rg * 64 + row) * DD + d] = h[i];
    }
}

extern "C" void kernel_launch(void* const* d_in, const int* in_sizes, int n_in,
                              void* d_out, int out_size, void* d_ws, size_t ws_size,
                              hipStream_t stream)
{
    const float* state = (const float*)d_in[0];
    const float* Wih   = (const float*)d_in[1];
    const float* Whh   = (const float*)d_in[2];
    const float* bih   = (const float*)d_in[3];
    const float* bhh   = (const float*)d_in[4];
    const float* bc    = (const float*)d_in[5];
    const int*   rec   = (const int*)d_in[6];

    char* ws = (char*)d_ws;
    float*    spart = (float*)ws;                   // 2 KB (8 shards x 64 t)
    unsigned* bar   = (unsigned*)(ws + 2048);       // 4 KB (32 groups + root)
    unsigned* garr  = (unsigned*)(ws + 6144);       // 1 KB (8 rg x 64B)
    f16*   ApB   = (f16*)(ws + 8192);               // 2 x 1 MB
    f16*   Wp0   = ApB + 2 * APCNT;                 // 6.29 MB
    f16*   Wp1   = Wp0 + WPCNT;                     // 6.29 MB
    float* hist  = (float*)(Wp1 + WPCNT);           // 8 MB (256x8x1024 f32)
    float* out   = (float*)d_out;

    hipMemsetAsync(ws, 0, 8192, stream);            // spart + bar + garr
    // rec==0 robustness: output = state if no iteration runs
    hipMemcpyAsync(out, state, (size_t)NELEM * sizeof(float),
                   hipMemcpyDeviceToDevice, stream);

    conv_w<<<dim3(NSTRIPS * WKSTEPS * 64 / 256), 256, 0, stream>>>(Wih, Whh, Wp0, Wp1);
    conv_a<<<dim3(MSTRIPS * AKSTEPS * 64 / 256), 256, 0, stream>>>(state, ApB);

    gru_persist<<<dim3(NBLK), dim3(512), 0, stream>>>(
        ApB, Wp0, Wp1, bih, bhh, out, spart, bc, rec, bar, garr, hist);
}